// Round 1
// baseline (1094.153 us; speedup 1.0000x reference)
//
#include <hip/hip_runtime.h>
#include <hip/hip_bf16.h>

#define E_NUM 8
#define KSEL 2

typedef __attribute__((ext_vector_type(8))) short short8;
typedef __attribute__((ext_vector_type(4))) float f32x4;

// fp32 -> bf16 round-to-nearest-even (finite inputs)
__device__ inline unsigned short f2bf(float f) {
  unsigned int u = __float_as_uint(f);
  unsigned int lsb = (u >> 16) & 1u;
  u += 0x7fffu + lsb;
  return (unsigned short)(u >> 16);
}

// ---------------- x (fp32) -> xb (bf16) ----------------
__global__ __launch_bounds__(256) void cvt_bf16_kernel(const float* __restrict__ in,
                                                       unsigned short* __restrict__ out,
                                                       long n) {
  long i = ((long)blockIdx.x * 256 + threadIdx.x) * 8;
  if (i >= n) return;
  float4 a = *(const float4*)(in + i);
  float4 b = *(const float4*)(in + i + 4);
  union { unsigned short us[8]; uint4 v; } u;
  u.us[0] = f2bf(a.x); u.us[1] = f2bf(a.y); u.us[2] = f2bf(a.z); u.us[3] = f2bf(a.w);
  u.us[4] = f2bf(b.x); u.us[5] = f2bf(b.y); u.us[6] = f2bf(b.z); u.us[7] = f2bf(b.w);
  *(uint4*)(out + i) = u.v;
}

// ---------------- router: logits, top-2, gates (fp32, wave per token) ----------------
__global__ __launch_bounds__(256) void router_kernel(
    const float* __restrict__ x, const float* __restrict__ Wr, const float* __restrict__ br,
    int N, int C,
    int* __restrict__ top1, int* __restrict__ top2,
    float* __restrict__ g1, float* __restrict__ g2) {
  int wave = threadIdx.x >> 6;
  int lane = threadIdx.x & 63;
  int n = blockIdx.x * 4 + wave;
  if (n >= N) return;
  float acc[E_NUM];
#pragma unroll
  for (int e = 0; e < E_NUM; ++e) acc[e] = 0.f;
  const float* xr = x + (long)n * C;
  for (int c = lane; c < C; c += 64) {
    float xv = xr[c];
    const float* wr = Wr + (long)c * E_NUM;
    float4 w0 = *(const float4*)(wr);
    float4 w1 = *(const float4*)(wr + 4);
    acc[0] += xv * w0.x; acc[1] += xv * w0.y; acc[2] += xv * w0.z; acc[3] += xv * w0.w;
    acc[4] += xv * w1.x; acc[5] += xv * w1.y; acc[6] += xv * w1.z; acc[7] += xv * w1.w;
  }
#pragma unroll
  for (int off = 32; off > 0; off >>= 1)
#pragma unroll
    for (int e = 0; e < E_NUM; ++e) acc[e] += __shfl_xor(acc[e], off, 64);
  if (lane == 0) {
    float v1 = -3.4e38f, v2 = -3.4e38f; int i1 = 0, i2 = 0;
#pragma unroll
    for (int e = 0; e < E_NUM; ++e) {
      float v = acc[e] + br[e];
      if (v > v1) { v2 = v1; i2 = i1; v1 = v; i1 = e; }
      else if (v > v2) { v2 = v; i2 = e; }
    }
    float t = expf(v2 - v1);          // softmax over [v1, v2]
    float s = 1.f / (1.f + t);
    top1[n] = i1; top2[n] = i2;
    g1[n] = s;    g2[n] = t * s;
  }
}

// ---------------- rank/capacity scan: one block per expert ----------------
// Reproduces reference: rank = exclusive cumsum of sel over token order; keep rank < cap.
__global__ __launch_bounds__(1024) void scan_kernel(
    const int* __restrict__ top1, const int* __restrict__ top2,
    const float* __restrict__ g1, const float* __restrict__ g2,
    int N, int cap, int* __restrict__ buf, float* __restrict__ wgt) {
  const int e = blockIdx.x;
  const int t = threadIdx.x;
  const int TP = N / 1024;            // 8 for this problem
  __shared__ int sc[1024];
  int sel[8]; float gv[8];
  int tot = 0;
  const int base_n = t * TP;
#pragma unroll
  for (int i = 0; i < 8; ++i) {
    if (i >= TP) break;
    int n = base_n + i;
    int s1 = (top1[n] == e);
    int s2 = (top2[n] == e);
    sel[i] = s1 | s2;
    gv[i] = s1 ? g1[n] : g2[n];
    tot += sel[i];
  }
  sc[t] = tot;
  __syncthreads();
  for (int off = 1; off < 1024; off <<= 1) {   // Hillis-Steele inclusive scan
    int v = (t >= off) ? sc[t - off] : 0;
    __syncthreads();
    sc[t] += v;
    __syncthreads();
  }
  int base = sc[t] - tot;                      // exclusive prefix for this thread
  int count = sc[1023];
#pragma unroll
  for (int i = 0; i < 8; ++i) {
    if (i >= TP) break;
    if (sel[i]) {
      if (base < cap) {
        buf[e * cap + base] = base_n + i;
        wgt[e * cap + base] = gv[i];
      }
      ++base;
    }
  }
  for (int s = count + t; s < cap; s += 1024) {  // sentinel-fill empty slots
    buf[e * cap + s] = N;
    wgt[e * cap + s] = 0.f;
  }
}

// ---------------- tiled transpose: in [R][S] fp32 (+e*strideIn) -> out [S][R] bf16 ----------------
__global__ __launch_bounds__(256) void transpose_kernel(
    const float* __restrict__ in, unsigned short* __restrict__ out,
    int R, int S, long strideIn, long strideOut, int eGlobal) {
  __shared__ float tile[64][65];
  const float* src = in + (long)(eGlobal + blockIdx.z) * strideIn;
  unsigned short* dst = out + (long)blockIdx.z * strideOut;
  int s0 = blockIdx.x * 64, r0 = blockIdx.y * 64;
  int t = threadIdx.x;
  int rl = t >> 4, sl = (t & 15) * 4;
#pragma unroll
  for (int rr = 0; rr < 4; ++rr) {
    int r = rl + rr * 16;
    float4 v = *(const float4*)(src + (long)(r0 + r) * S + s0 + sl);
    tile[r][sl] = v.x; tile[r][sl + 1] = v.y; tile[r][sl + 2] = v.z; tile[r][sl + 3] = v.w;
  }
  __syncthreads();
#pragma unroll
  for (int it = 0; it < 2; ++it) {
    int idx = t + it * 256;
    int so = idx >> 3;          // output row (s-dim), 0..63
    int rc = (idx & 7) * 8;     // output col chunk (r-dim)
    union { unsigned short us[8]; uint4 v; } u;
#pragma unroll
    for (int j = 0; j < 8; ++j) u.us[j] = f2bf(tile[rc + j][so]);
    *(uint4*)(dst + (long)(s0 + so) * R + r0 + rc) = u.v;
  }
}

// ---------------- MFMA GEMM, 128x128 tile, 4 waves of 64x64, K-step 64 ----------------
// MODE 0: A = xb gathered via buf[expert], B = W1T[e] ([H][C] bf16), epilogue bias+GeLU -> h (bf16)
// MODE 1: A = h[e] dense,                B = W2T[e] ([C][H] bf16), epilogue bias*gate -> atomic add into out
template <int MODE>
__global__ __launch_bounds__(256) void moe_gemm(
    const unsigned short* __restrict__ A, const unsigned short* __restrict__ B,
    const int* __restrict__ buf, const float* __restrict__ wgt,
    const float* __restrict__ bias,
    unsigned short* __restrict__ Hout, float* __restrict__ Fout,
    int Kdim, int Nn, int cap, int Ntok,
    int eGlobal, long strideB, long strideH) {
  const int tid = threadIdx.x;
  const int lane = tid & 63;
  const int wave = tid >> 6;
  const int wr = wave >> 1, wc = wave & 1;
  const int eIdx = blockIdx.z;
  const int expert = eGlobal + eIdx;
  const int m0 = blockIdx.y * 128;
  const int n0 = blockIdx.x * 128;

  const unsigned short* Bexp = B + (long)eIdx * strideB;

  // K padded 64->72 elements (144B row stride): row r starts at bank 4r mod 32 -> worst 2-way (free)
  __shared__ unsigned short As[128][72];
  __shared__ unsigned short Bs[128][72];

  const unsigned short* aSrc[4];
  const unsigned short* bSrc[4];
#pragma unroll
  for (int q = 0; q < 4; ++q) {
    int idx = tid + q * 256;
    int r = idx >> 3;
    int kc = (idx & 7) * 8;
    if (MODE == 0) {
      int tok = buf[expert * cap + m0 + r];
      aSrc[q] = (tok < Ntok) ? (A + (long)tok * Kdim + kc) : nullptr;  // sentinel row -> zeros
    } else {
      aSrc[q] = A + (long)eIdx * strideH + (long)(m0 + r) * Kdim + kc;
    }
    bSrc[q] = Bexp + (long)(n0 + r) * Kdim + kc;
  }

  f32x4 acc[4][4];
#pragma unroll
  for (int i = 0; i < 4; ++i)
#pragma unroll
    for (int j = 0; j < 4; ++j) acc[i][j] = {0.f, 0.f, 0.f, 0.f};

  const int rA = (lane & 15);
  const int kOff = (lane >> 4) * 8;

  for (int k0 = 0; k0 < Kdim; k0 += 64) {
#pragma unroll
    for (int q = 0; q < 4; ++q) {
      int idx = tid + q * 256;
      int r = idx >> 3;
      int kc = (idx & 7) * 8;
      uint4 av = aSrc[q] ? *(const uint4*)(aSrc[q] + k0) : make_uint4(0u, 0u, 0u, 0u);
      *(uint4*)(&As[r][kc]) = av;
      *(uint4*)(&Bs[r][kc]) = *(const uint4*)(bSrc[q] + k0);
    }
    __syncthreads();
#pragma unroll
    for (int ks = 0; ks < 2; ++ks) {
      short8 af[4], bfr[4];
      int kb = ks * 32 + kOff;
#pragma unroll
      for (int mi = 0; mi < 4; ++mi)
        af[mi] = *(const short8*)(&As[wr * 64 + mi * 16 + rA][kb]);
#pragma unroll
      for (int ni = 0; ni < 4; ++ni)
        bfr[ni] = *(const short8*)(&Bs[wc * 64 + ni * 16 + rA][kb]);
#pragma unroll
      for (int mi = 0; mi < 4; ++mi)
#pragma unroll
        for (int ni = 0; ni < 4; ++ni)
          acc[mi][ni] = __builtin_amdgcn_mfma_f32_16x16x32_bf16(af[mi], bfr[ni], acc[mi][ni], 0, 0, 0);
    }
    __syncthreads();
  }

  if (MODE == 0) {
    const float* b1 = bias + (long)expert * Nn;
    unsigned short* hExp = Hout + (long)eIdx * strideH;
#pragma unroll
    for (int ni = 0; ni < 4; ++ni) {
      int col = n0 + wc * 64 + ni * 16 + (lane & 15);
      float bv = b1[col];
#pragma unroll
      for (int mi = 0; mi < 4; ++mi) {
        int row0 = m0 + wr * 64 + mi * 16 + (lane >> 4) * 4;
#pragma unroll
        for (int r = 0; r < 4; ++r) {
          float v = acc[mi][ni][r] + bv;
          float gl = 0.5f * v * (1.f + erff(v * 0.70710678118654752f));  // exact GeLU
          hExp[(long)(row0 + r) * Nn + col] = f2bf(gl);
        }
      }
    }
  } else {
    const float* b2 = bias + (long)expert * Nn;
#pragma unroll
    for (int mi = 0; mi < 4; ++mi) {
      int row0 = m0 + wr * 64 + mi * 16 + (lane >> 4) * 4;
#pragma unroll
      for (int r = 0; r < 4; ++r) {
        int slot = row0 + r;
        int tok = buf[expert * cap + slot];
        if (tok >= Ntok) continue;     // dropped/sentinel slot contributes nothing
        float w = wgt[expert * cap + slot];
#pragma unroll
        for (int ni = 0; ni < 4; ++ni) {
          int col = n0 + wc * 64 + ni * 16 + (lane & 15);
          float v = (acc[mi][ni][r] + b2[col]) * w;
          unsafeAtomicAdd(Fout + (long)tok * Nn + col, v);
        }
      }
    }
  }
}

// ---------------- host launcher ----------------
extern "C" void kernel_launch(void* const* d_in, const int* in_sizes, int n_in,
                              void* d_out, int out_size, void* d_ws, size_t ws_size,
                              hipStream_t stream) {
  const float* x  = (const float*)d_in[0];
  const float* Wr = (const float*)d_in[1];
  const float* br = (const float*)d_in[2];
  const float* W1 = (const float*)d_in[3];
  const float* b1 = (const float*)d_in[4];
  const float* W2 = (const float*)d_in[5];
  const float* b2 = (const float*)d_in[6];
  float* out = (float*)d_out;

  const int C = in_sizes[1] / E_NUM;            // Wr is (C,E)
  const long NC = in_sizes[0];
  const int N = (int)(NC / C);
  const int H = in_sizes[4] / E_NUM;            // b1 is (E,H)
  const int cap = N * KSEL / E_NUM;             // int(N*K/E * 1.0)

  char* p = (char*)d_ws;
  auto alloc = [&](size_t bytes) { char* r = p; p += (bytes + 255) & ~255ULL; return r; };

  unsigned short* xb = (unsigned short*)alloc((size_t)N * C * 2);
  int*   top1 = (int*)alloc((size_t)N * 4);
  int*   top2 = (int*)alloc((size_t)N * 4);
  float* g1   = (float*)alloc((size_t)N * 4);
  float* g2   = (float*)alloc((size_t)N * 4);
  int*   buf  = (int*)alloc((size_t)E_NUM * cap * 4);
  float* wgt  = (float*)alloc((size_t)E_NUM * cap * 4);
  size_t commonBytes = (size_t)(p - (char*)d_ws);

  const size_t w1tFull = (size_t)E_NUM * C * H * 2;
  const size_t w2tFull = (size_t)E_NUM * H * C * 2;
  const size_t hFull   = (size_t)E_NUM * cap * H * 2;
  const bool full = ws_size >= commonBytes + w1tFull + w2tFull + hFull + 4096;

  hipMemsetAsync(d_out, 0, (size_t)out_size * sizeof(float), stream);
  cvt_bf16_kernel<<<(int)(((long)N * C) / (256 * 8)), 256, 0, stream>>>(x, xb, (long)N * C);
  router_kernel<<<(N + 3) / 4, 256, 0, stream>>>(x, Wr, br, N, C, top1, top2, g1, g2);
  scan_kernel<<<E_NUM, 1024, 0, stream>>>(top1, top2, g1, g2, N, cap, buf, wgt);

  if (full) {
    unsigned short* W1T = (unsigned short*)alloc(w1tFull);
    unsigned short* W2T = (unsigned short*)alloc(w2tFull);
    unsigned short* hb  = (unsigned short*)alloc(hFull);
    transpose_kernel<<<dim3(H / 64, C / 64, E_NUM), 256, 0, stream>>>(
        W1, W1T, C, H, (long)C * H, (long)C * H, 0);
    moe_gemm<0><<<dim3(H / 128, cap / 128, E_NUM), 256, 0, stream>>>(
        xb, W1T, buf, wgt, b1, hb, nullptr, C, H, cap, N, 0, (long)C * H, (long)cap * H);
    transpose_kernel<<<dim3(C / 64, H / 64, E_NUM), 256, 0, stream>>>(
        W2, W2T, H, C, (long)H * C, (long)H * C, 0);
    moe_gemm<1><<<dim3(C / 128, cap / 128, E_NUM), 256, 0, stream>>>(
        hb, W2T, buf, wgt, b2, nullptr, out, H, C, cap, N, 0, (long)H * C, (long)cap * H);
  } else {
    unsigned short* w1t = (unsigned short*)alloc((size_t)C * H * 2);
    unsigned short* w2t = (unsigned short*)alloc((size_t)H * C * 2);
    unsigned short* hb  = (unsigned short*)alloc((size_t)cap * H * 2);
    for (int e = 0; e < E_NUM; ++e) {
      transpose_kernel<<<dim3(H / 64, C / 64, 1), 256, 0, stream>>>(
          W1, w1t, C, H, (long)C * H, 0, e);
      moe_gemm<0><<<dim3(H / 128, cap / 128, 1), 256, 0, stream>>>(
          xb, w1t, buf, wgt, b1, hb, nullptr, C, H, cap, N, e, 0, 0);
      transpose_kernel<<<dim3(C / 64, H / 64, 1), 256, 0, stream>>>(
          W2, w2t, H, C, (long)H * C, 0, e);
      moe_gemm<1><<<dim3(C / 128, cap / 128, 1), 256, 0, stream>>>(
          hb, w2t, buf, wgt, b2, nullptr, out, H, C, cap, N, e, 0, 0);
    }
  }
}

// Round 2
// 909.636 us; speedup vs baseline: 1.2028x; 1.2028x over previous
//
#include <hip/hip_runtime.h>
#include <hip/hip_bf16.h>

#define E_NUM 8
#define KSEL 2

typedef __attribute__((ext_vector_type(8))) short short8;
typedef __attribute__((ext_vector_type(4))) float f32x4;

// fp32 -> bf16 round-to-nearest-even (finite inputs)
__device__ inline unsigned short f2bf(float f) {
  unsigned int u = __float_as_uint(f);
  unsigned int lsb = (u >> 16) & 1u;
  u += 0x7fffu + lsb;
  return (unsigned short)(u >> 16);
}

// async global->LDS, 16B per lane; LDS dest is wave-uniform base + lane*16
__device__ inline void gload16(const unsigned short* g, unsigned short* l) {
  __builtin_amdgcn_global_load_lds(
      (const __attribute__((address_space(1))) unsigned int*)(const void*)g,
      (__attribute__((address_space(3))) unsigned int*)(void*)l, 16, 0, 0);
}

// ---------------- x (fp32) -> xb (bf16) ----------------
__global__ __launch_bounds__(256) void cvt_bf16_kernel(const float* __restrict__ in,
                                                       unsigned short* __restrict__ out,
                                                       long n) {
  long i = ((long)blockIdx.x * 256 + threadIdx.x) * 8;
  if (i >= n) return;
  float4 a = *(const float4*)(in + i);
  float4 b = *(const float4*)(in + i + 4);
  union { unsigned short us[8]; uint4 v; } u;
  u.us[0] = f2bf(a.x); u.us[1] = f2bf(a.y); u.us[2] = f2bf(a.z); u.us[3] = f2bf(a.w);
  u.us[4] = f2bf(b.x); u.us[5] = f2bf(b.y); u.us[6] = f2bf(b.z); u.us[7] = f2bf(b.w);
  *(uint4*)(out + i) = u.v;
}

// ---------------- router: logits, top-2, gates (fp32, wave per token) ----------------
__global__ __launch_bounds__(256) void router_kernel(
    const float* __restrict__ x, const float* __restrict__ Wr, const float* __restrict__ br,
    int N, int C,
    int* __restrict__ top1, int* __restrict__ top2,
    float* __restrict__ g1, float* __restrict__ g2) {
  int wave = threadIdx.x >> 6;
  int lane = threadIdx.x & 63;
  int n = blockIdx.x * 4 + wave;
  if (n >= N) return;
  float acc[E_NUM];
#pragma unroll
  for (int e = 0; e < E_NUM; ++e) acc[e] = 0.f;
  const float* xr = x + (long)n * C;
  for (int c = lane; c < C; c += 64) {
    float xv = xr[c];
    const float* wr = Wr + (long)c * E_NUM;
    float4 w0 = *(const float4*)(wr);
    float4 w1 = *(const float4*)(wr + 4);
    acc[0] += xv * w0.x; acc[1] += xv * w0.y; acc[2] += xv * w0.z; acc[3] += xv * w0.w;
    acc[4] += xv * w1.x; acc[5] += xv * w1.y; acc[6] += xv * w1.z; acc[7] += xv * w1.w;
  }
#pragma unroll
  for (int off = 32; off > 0; off >>= 1)
#pragma unroll
    for (int e = 0; e < E_NUM; ++e) acc[e] += __shfl_xor(acc[e], off, 64);
  if (lane == 0) {
    float v1 = -3.4e38f, v2 = -3.4e38f; int i1 = 0, i2 = 0;
#pragma unroll
    for (int e = 0; e < E_NUM; ++e) {
      float v = acc[e] + br[e];
      if (v > v1) { v2 = v1; i2 = i1; v1 = v; i1 = e; }
      else if (v > v2) { v2 = v; i2 = e; }
    }
    float t = expf(v2 - v1);          // softmax over [v1, v2]
    float s = 1.f / (1.f + t);
    top1[n] = i1; top2[n] = i2;
    g1[n] = s;    g2[n] = t * s;
  }
}

// ---------------- rank/capacity scan: one block per expert ----------------
__global__ __launch_bounds__(1024) void scan_kernel(
    const int* __restrict__ top1, const int* __restrict__ top2,
    const float* __restrict__ g1, const float* __restrict__ g2,
    int N, int cap, int* __restrict__ buf, float* __restrict__ wgt) {
  const int e = blockIdx.x;
  const int t = threadIdx.x;
  const int TP = N / 1024;            // 8 for this problem
  __shared__ int sc[1024];
  int sel[8]; float gv[8];
  int tot = 0;
  const int base_n = t * TP;
#pragma unroll
  for (int i = 0; i < 8; ++i) {
    if (i >= TP) break;
    int n = base_n + i;
    int s1 = (top1[n] == e);
    int s2 = (top2[n] == e);
    sel[i] = s1 | s2;
    gv[i] = s1 ? g1[n] : g2[n];
    tot += sel[i];
  }
  sc[t] = tot;
  __syncthreads();
  for (int off = 1; off < 1024; off <<= 1) {   // Hillis-Steele inclusive scan
    int v = (t >= off) ? sc[t - off] : 0;
    __syncthreads();
    sc[t] += v;
    __syncthreads();
  }
  int base = sc[t] - tot;                      // exclusive prefix for this thread
  int count = sc[1023];
#pragma unroll
  for (int i = 0; i < 8; ++i) {
    if (i >= TP) break;
    if (sel[i]) {
      if (base < cap) {
        buf[e * cap + base] = base_n + i;
        wgt[e * cap + base] = gv[i];
      }
      ++base;
    }
  }
  for (int s = count + t; s < cap; s += 1024) {  // sentinel-fill empty slots
    buf[e * cap + s] = N;
    wgt[e * cap + s] = 0.f;
  }
}

// ---------------- tiled transpose: in [R][S] fp32 (+e*strideIn) -> out [S][R] bf16 ----------------
__global__ __launch_bounds__(256) void transpose_kernel(
    const float* __restrict__ in, unsigned short* __restrict__ out,
    int R, int S, long strideIn, long strideOut, int eGlobal) {
  __shared__ float tile[64][65];
  const float* src = in + (long)(eGlobal + blockIdx.z) * strideIn;
  unsigned short* dst = out + (long)blockIdx.z * strideOut;
  int s0 = blockIdx.x * 64, r0 = blockIdx.y * 64;
  int t = threadIdx.x;
  int rl = t >> 4, sl = (t & 15) * 4;
#pragma unroll
  for (int rr = 0; rr < 4; ++rr) {
    int r = rl + rr * 16;
    float4 v = *(const float4*)(src + (long)(r0 + r) * S + s0 + sl);
    tile[r][sl] = v.x; tile[r][sl + 1] = v.y; tile[r][sl + 2] = v.z; tile[r][sl + 3] = v.w;
  }
  __syncthreads();
#pragma unroll
  for (int it = 0; it < 2; ++it) {
    int idx = t + it * 256;
    int so = idx >> 3;          // output row (s-dim), 0..63
    int rc = (idx & 7) * 8;     // output col chunk (r-dim)
    union { unsigned short us[8]; uint4 v; } u;
#pragma unroll
    for (int j = 0; j < 8; ++j) u.us[j] = f2bf(tile[rc + j][so]);
    *(uint4*)(dst + (long)(s0 + so) * R + r0 + rc) = u.v;
  }
}

// ---------------- MFMA GEMM, 128x128 tile, 4 waves of 64x64, K-step 64 ----------------
// m97 structure: global_load_lds width-16 staging into LINEAR [128][64] LDS,
// with both-sides XOR swizzle: LDS byte d holds element (r=d>>7, cbyte=(d&127)^((r&7)<<4)).
// MODE 0: A = xb gathered via buf[expert], B = W1T[e] ([H][C]), epilogue bias+GeLU -> h (bf16)
// MODE 1: A = h[e] dense,                 B = W2T[e] ([C][H]), epilogue bias, *gate, atomic-add to out
template <int MODE>
__global__ __launch_bounds__(256) void moe_gemm(
    const unsigned short* __restrict__ A, const unsigned short* __restrict__ B,
    const int* __restrict__ buf, const float* __restrict__ wgt,
    const float* __restrict__ bias, const unsigned short* __restrict__ zp,
    unsigned short* __restrict__ Hout, float* __restrict__ Fout,
    int Kdim, int Nn, int cap, int Ntok,
    int eGlobal, long strideB, long strideH) {
  const int tid = threadIdx.x;
  const int lane = tid & 63;
  const int wave = tid >> 6;
  const int wr = wave >> 1, wc = wave & 1;
  const int eIdx = blockIdx.z;
  const int expert = eGlobal + eIdx;
  const int m0 = blockIdx.y * 128;
  const int n0 = blockIdx.x * 128;

  const unsigned short* Bexp = B + (long)eIdx * strideB;

  __shared__ unsigned short As[128 * 64];
  __shared__ unsigned short Bs[128 * 64];

  // staging geometry: dest chunk idx = q*256+tid, dest byte = idx*16,
  // row r = idx>>3, source col-byte = ((idx&7)<<4) ^ ((r&7)<<4)  (involution)
  const unsigned short* aRow[4];
  const unsigned short* bRow[4];
  int aStep[4];
#pragma unroll
  for (int q = 0; q < 4; ++q) {
    int idx = tid + q * 256;
    int r = idx >> 3;
    int cOff = ((((idx & 7) << 4) ^ ((r & 7) << 4)) >> 1);  // element offset in row
    if (MODE == 0) {
      int tok = buf[expert * cap + m0 + r];
      bool ok = (tok < Ntok);
      aRow[q] = ok ? (A + (long)tok * Kdim + cOff) : (zp + cOff);  // sentinel -> zero page
      aStep[q] = ok ? 64 : 0;
    } else {
      aRow[q] = A + (long)eIdx * strideH + (long)(m0 + r) * Kdim + cOff;
      aStep[q] = 64;
    }
    bRow[q] = Bexp + (long)(n0 + r) * Kdim + cOff;
  }

  f32x4 acc[4][4];
#pragma unroll
  for (int i = 0; i < 4; ++i)
#pragma unroll
    for (int j = 0; j < 4; ++j) acc[i][j] = {0.f, 0.f, 0.f, 0.f};

  const int rA = lane & 15;
  const int kByte = (lane >> 4) * 16;       // byte offset of this lane's 8-elem k-chunk
  const int wbase = wave * 64 * 8;          // wave-uniform LDS dest base (shorts)

  for (int kt = 0; kt < Kdim; kt += 64) {
#pragma unroll
    for (int q = 0; q < 4; ++q) {
      gload16(aRow[q], As + wbase + q * 2048);
      gload16(bRow[q], Bs + wbase + q * 2048);
      aRow[q] += aStep[q];
      bRow[q] += 64;
    }
    __syncthreads();   // compiler drains vmcnt(0) here -> staged data visible
#pragma unroll
    for (int ks = 0; ks < 2; ++ks) {
      short8 af[4], bg[4];
#pragma unroll
      for (int mi = 0; mi < 4; ++mi) {
        int row = wr * 64 + mi * 16 + rA;
        int o = row * 128 + ks * 64 + kByte;
        o ^= (row & 7) << 4;                 // same involution as staging
        af[mi] = *(const short8*)((const char*)As + o);
      }
#pragma unroll
      for (int ni = 0; ni < 4; ++ni) {
        int row = wc * 64 + ni * 16 + rA;
        int o = row * 128 + ks * 64 + kByte;
        o ^= (row & 7) << 4;
        bg[ni] = *(const short8*)((const char*)Bs + o);
      }
#pragma unroll
      for (int mi = 0; mi < 4; ++mi)
#pragma unroll
        for (int ni = 0; ni < 4; ++ni)
          acc[mi][ni] = __builtin_amdgcn_mfma_f32_16x16x32_bf16(af[mi], bg[ni], acc[mi][ni], 0, 0, 0);
    }
    __syncthreads();
  }

  if (MODE == 0) {
    const float* b1 = bias + (long)expert * Nn;
    unsigned short* hExp = Hout + (long)eIdx * strideH;
#pragma unroll
    for (int ni = 0; ni < 4; ++ni) {
      int col = n0 + wc * 64 + ni * 16 + (lane & 15);
      float bv = b1[col];
#pragma unroll
      for (int mi = 0; mi < 4; ++mi) {
        int row0 = m0 + wr * 64 + mi * 16 + (lane >> 4) * 4;
#pragma unroll
        for (int r = 0; r < 4; ++r) {
          float v = acc[mi][ni][r] + bv;
          float gl = 0.5f * v * (1.f + erff(v * 0.70710678118654752f));  // exact GeLU
          hExp[(long)(row0 + r) * Nn + col] = f2bf(gl);
        }
      }
    }
  } else {
    const float* b2 = bias + (long)expert * Nn;
#pragma unroll
    for (int mi = 0; mi < 4; ++mi) {
      int row0 = m0 + wr * 64 + mi * 16 + (lane >> 4) * 4;
#pragma unroll
      for (int r = 0; r < 4; ++r) {
        int slot = row0 + r;
        int tok = buf[expert * cap + slot];
        if (tok >= Ntok) continue;     // dropped/sentinel slot contributes nothing
        float w = wgt[expert * cap + slot];
#pragma unroll
        for (int ni = 0; ni < 4; ++ni) {
          int col = n0 + wc * 64 + ni * 16 + (lane & 15);
          float v = (acc[mi][ni][r] + b2[col]) * w;
          unsafeAtomicAdd(Fout + (long)tok * Nn + col, v);
        }
      }
    }
  }
}

// ---------------- host launcher ----------------
extern "C" void kernel_launch(void* const* d_in, const int* in_sizes, int n_in,
                              void* d_out, int out_size, void* d_ws, size_t ws_size,
                              hipStream_t stream) {
  const float* x  = (const float*)d_in[0];
  const float* Wr = (const float*)d_in[1];
  const float* br = (const float*)d_in[2];
  const float* W1 = (const float*)d_in[3];
  const float* b1 = (const float*)d_in[4];
  const float* W2 = (const float*)d_in[5];
  const float* b2 = (const float*)d_in[6];
  float* out = (float*)d_out;

  const int C = in_sizes[1] / E_NUM;            // Wr is (C,E)
  const long NC = in_sizes[0];
  const int N = (int)(NC / C);
  const int H = in_sizes[4] / E_NUM;            // b1 is (E,H)
  const int cap = N * KSEL / E_NUM;             // int(N*K/E * 1.0)

  char* p = (char*)d_ws;
  auto alloc = [&](size_t bytes) { char* r = p; p += (bytes + 255) & ~255ULL; return r; };

  unsigned short* xb = (unsigned short*)alloc((size_t)N * C * 2);
  int*   top1 = (int*)alloc((size_t)N * 4);
  int*   top2 = (int*)alloc((size_t)N * 4);
  float* g1   = (float*)alloc((size_t)N * 4);
  float* g2   = (float*)alloc((size_t)N * 4);
  int*   buf  = (int*)alloc((size_t)E_NUM * cap * 4);
  float* wgt  = (float*)alloc((size_t)E_NUM * cap * 4);
  unsigned short* zp = (unsigned short*)alloc(256);   // zero page for sentinel rows
  size_t commonBytes = (size_t)(p - (char*)d_ws);

  const size_t w1tFull = (size_t)E_NUM * C * H * 2;
  const size_t w2tFull = (size_t)E_NUM * H * C * 2;
  const size_t hFull   = (size_t)E_NUM * cap * H * 2;
  const bool full = ws_size >= commonBytes + w1tFull + w2tFull + hFull + 4096;

  hipMemsetAsync(d_out, 0, (size_t)out_size * sizeof(float), stream);
  hipMemsetAsync(zp, 0, 256, stream);
  cvt_bf16_kernel<<<(int)(((long)N * C) / (256 * 8)), 256, 0, stream>>>(x, xb, (long)N * C);
  router_kernel<<<(N + 3) / 4, 256, 0, stream>>>(x, Wr, br, N, C, top1, top2, g1, g2);
  scan_kernel<<<E_NUM, 1024, 0, stream>>>(top1, top2, g1, g2, N, cap, buf, wgt);

  if (full) {
    unsigned short* W1T = (unsigned short*)alloc(w1tFull);
    unsigned short* W2T = (unsigned short*)alloc(w2tFull);
    unsigned short* hb  = (unsigned short*)alloc(hFull);
    transpose_kernel<<<dim3(H / 64, C / 64, E_NUM), 256, 0, stream>>>(
        W1, W1T, C, H, (long)C * H, (long)C * H, 0);
    moe_gemm<0><<<dim3(H / 128, cap / 128, E_NUM), 256, 0, stream>>>(
        xb, W1T, buf, wgt, b1, zp, hb, nullptr, C, H, cap, N, 0, (long)C * H, (long)cap * H);
    transpose_kernel<<<dim3(C / 64, H / 64, E_NUM), 256, 0, stream>>>(
        W2, W2T, H, C, (long)H * C, (long)H * C, 0);
    moe_gemm<1><<<dim3(C / 128, cap / 128, E_NUM), 256, 0, stream>>>(
        hb, W2T, buf, wgt, b2, zp, nullptr, out, H, C, cap, N, 0, (long)H * C, (long)cap * H);
  } else {
    unsigned short* w1t = (unsigned short*)alloc((size_t)C * H * 2);
    unsigned short* w2t = (unsigned short*)alloc((size_t)H * C * 2);
    unsigned short* hb  = (unsigned short*)alloc((size_t)cap * H * 2);
    for (int e = 0; e < E_NUM; ++e) {
      transpose_kernel<<<dim3(H / 64, C / 64, 1), 256, 0, stream>>>(
          W1, w1t, C, H, (long)C * H, 0, e);
      moe_gemm<0><<<dim3(H / 128, cap / 128, 1), 256, 0, stream>>>(
          xb, w1t, buf, wgt, b1, zp, hb, nullptr, C, H, cap, N, e, 0, 0);
      transpose_kernel<<<dim3(C / 64, H / 64, 1), 256, 0, stream>>>(
          W2, w2t, H, C, (long)H * C, 0, e);
      moe_gemm<1><<<dim3(C / 128, cap / 128, 1), 256, 0, stream>>>(
          hb, w2t, buf, wgt, b2, zp, nullptr, out, H, C, cap, N, e, 0, 0);
    }
  }
}

// Round 5
// 851.132 us; speedup vs baseline: 1.2855x; 1.0687x over previous
//
#include <hip/hip_runtime.h>
#include <hip/hip_bf16.h>

#define E_NUM 8
#define KSEL 2

typedef __attribute__((ext_vector_type(8))) short short8;
typedef __attribute__((ext_vector_type(4))) float f32x4;

// fp32 -> bf16 round-to-nearest-even (finite inputs)
__device__ inline unsigned short f2bf(float f) {
  unsigned int u = __float_as_uint(f);
  unsigned int lsb = (u >> 16) & 1u;
  u += 0x7fffu + lsb;
  return (unsigned short)(u >> 16);
}

// async global->LDS, 16B per lane; LDS dest is wave-uniform base + lane*16
__device__ inline void gload16(const unsigned short* g, unsigned short* l) {
  __builtin_amdgcn_global_load_lds(
      (const __attribute__((address_space(1))) unsigned int*)(const void*)g,
      (__attribute__((address_space(3))) unsigned int*)(void*)l, 16, 0, 0);
}

// ---------------- x (fp32) -> xb (bf16) ----------------
__global__ __launch_bounds__(256) void cvt_bf16_kernel(const float* __restrict__ in,
                                                       unsigned short* __restrict__ out,
                                                       long n) {
  long i = ((long)blockIdx.x * 256 + threadIdx.x) * 8;
  if (i >= n) return;
  float4 a = *(const float4*)(in + i);
  float4 b = *(const float4*)(in + i + 4);
  union { unsigned short us[8]; uint4 v; } u;
  u.us[0] = f2bf(a.x); u.us[1] = f2bf(a.y); u.us[2] = f2bf(a.z); u.us[3] = f2bf(a.w);
  u.us[4] = f2bf(b.x); u.us[5] = f2bf(b.y); u.us[6] = f2bf(b.z); u.us[7] = f2bf(b.w);
  *(uint4*)(out + i) = u.v;
}

// ---------------- router: logits, top-2, gates (fp32, wave per token) ----------------
__global__ __launch_bounds__(256) void router_kernel(
    const float* __restrict__ x, const float* __restrict__ Wr, const float* __restrict__ br,
    int N, int C,
    int* __restrict__ top1, int* __restrict__ top2,
    float* __restrict__ g1, float* __restrict__ g2) {
  int wave = threadIdx.x >> 6;
  int lane = threadIdx.x & 63;
  int n = blockIdx.x * 4 + wave;
  if (n >= N) return;
  float acc[E_NUM];
#pragma unroll
  for (int e = 0; e < E_NUM; ++e) acc[e] = 0.f;
  const float* xr = x + (long)n * C;
  for (int c = lane; c < C; c += 64) {
    float xv = xr[c];
    const float* wr = Wr + (long)c * E_NUM;
    float4 w0 = *(const float4*)(wr);
    float4 w1 = *(const float4*)(wr + 4);
    acc[0] += xv * w0.x; acc[1] += xv * w0.y; acc[2] += xv * w0.z; acc[3] += xv * w0.w;
    acc[4] += xv * w1.x; acc[5] += xv * w1.y; acc[6] += xv * w1.z; acc[7] += xv * w1.w;
  }
#pragma unroll
  for (int off = 32; off > 0; off >>= 1)
#pragma unroll
    for (int e = 0; e < E_NUM; ++e) acc[e] += __shfl_xor(acc[e], off, 64);
  if (lane == 0) {
    float v1 = -3.4e38f, v2 = -3.4e38f; int i1 = 0, i2 = 0;
#pragma unroll
    for (int e = 0; e < E_NUM; ++e) {
      float v = acc[e] + br[e];
      if (v > v1) { v2 = v1; i2 = i1; v1 = v; i1 = e; }
      else if (v > v2) { v2 = v; i2 = e; }
    }
    float t = expf(v2 - v1);          // softmax over [v1, v2]
    float s = 1.f / (1.f + t);
    top1[n] = i1; top2[n] = i2;
    g1[n] = s;    g2[n] = t * s;
  }
}

// ---------------- rank/capacity scan: one block per expert ----------------
__global__ __launch_bounds__(1024) void scan_kernel(
    const int* __restrict__ top1, const int* __restrict__ top2,
    const float* __restrict__ g1, const float* __restrict__ g2,
    int N, int cap, int* __restrict__ buf, float* __restrict__ wgt) {
  const int e = blockIdx.x;
  const int t = threadIdx.x;
  const int TP = N / 1024;            // 8 for this problem
  __shared__ int sc[1024];
  int sel[8]; float gv[8];
  int tot = 0;
  const int base_n = t * TP;
#pragma unroll
  for (int i = 0; i < 8; ++i) {
    if (i >= TP) break;
    int n = base_n + i;
    int s1 = (top1[n] == e);
    int s2 = (top2[n] == e);
    sel[i] = s1 | s2;
    gv[i] = s1 ? g1[n] : g2[n];
    tot += sel[i];
  }
  sc[t] = tot;
  __syncthreads();
  for (int off = 1; off < 1024; off <<= 1) {   // Hillis-Steele inclusive scan
    int v = (t >= off) ? sc[t - off] : 0;
    __syncthreads();
    sc[t] += v;
    __syncthreads();
  }
  int base = sc[t] - tot;                      // exclusive prefix for this thread
  int count = sc[1023];
#pragma unroll
  for (int i = 0; i < 8; ++i) {
    if (i >= TP) break;
    if (sel[i]) {
      if (base < cap) {
        buf[e * cap + base] = base_n + i;
        wgt[e * cap + base] = gv[i];
      }
      ++base;
    }
  }
  for (int s = count + t; s < cap; s += 1024) {  // sentinel-fill empty slots
    buf[e * cap + s] = N;
    wgt[e * cap + s] = 0.f;
  }
}

// ---------------- tiled transpose: in [R][S] fp32 (+e*strideIn) -> out [S][R] bf16 ----------------
__global__ __launch_bounds__(256) void transpose_kernel(
    const float* __restrict__ in, unsigned short* __restrict__ out,
    int R, int S, long strideIn, long strideOut, int eGlobal) {
  __shared__ float tile[64][65];
  const float* src = in + (long)(eGlobal + blockIdx.z) * strideIn;
  unsigned short* dst = out + (long)blockIdx.z * strideOut;
  int s0 = blockIdx.x * 64, r0 = blockIdx.y * 64;
  int t = threadIdx.x;
  int rl = t >> 4, sl = (t & 15) * 4;
#pragma unroll
  for (int rr = 0; rr < 4; ++rr) {
    int r = rl + rr * 16;
    float4 v = *(const float4*)(src + (long)(r0 + r) * S + s0 + sl);
    tile[r][sl] = v.x; tile[r][sl + 1] = v.y; tile[r][sl + 2] = v.z; tile[r][sl + 3] = v.w;
  }
  __syncthreads();
#pragma unroll
  for (int it = 0; it < 2; ++it) {
    int idx = t + it * 256;
    int so = idx >> 3;          // output row (s-dim), 0..63
    int rc = (idx & 7) * 8;     // output col chunk (r-dim)
    union { unsigned short us[8]; uint4 v; } u;
#pragma unroll
    for (int j = 0; j < 8; ++j) u.us[j] = f2bf(tile[rc + j][so]);
    *(uint4*)(dst + (long)(s0 + so) * R + r0 + rc) = u.v;
  }
}

// ---------------- MFMA GEMM, 128x128 tile, 4 waves of 64x64, K-step 64 ----------------
// Double-buffered global_load_lds staging (T3 minimum 2-phase), linear LDS + both-sides
// XOR swizzle (byte d holds element (r=d>>7, cbyte=(d&127)^((r&7)<<4))).
// 1-D grid, XCD-bijective swizzle + B-panel-major decode: each XCD owns a contiguous
// logical range (= one expert here); 16 consecutive blocks share one B panel (L2-resident).
// MODE 0: A = xb gathered via buf[expert], B = W1T[e] ([H][C]), epilogue bias+GeLU -> h (bf16)
// MODE 1: A = h[e] dense,                 B = W2T[e] ([C][H]), epilogue bias, *gate, atomic-add
template <int MODE>
__global__ __launch_bounds__(256) void moe_gemm(
    const unsigned short* __restrict__ A, const unsigned short* __restrict__ B,
    const int* __restrict__ buf, const float* __restrict__ wgt,
    const float* __restrict__ bias, const unsigned short* __restrict__ zp,
    unsigned short* __restrict__ Hout, float* __restrict__ Fout,
    int Kdim, int Nn, int cap, int Ntok,
    int eGlobal, long strideB, long strideH, int nx, int ny) {
  const int tid = threadIdx.x;
  const int lane = tid & 63;
  const int wave = tid >> 6;
  const int wr = wave >> 1, wc = wave & 1;

  // ---- block-id swizzle: contiguous logical range per XCD, B-panel-major within ----
  const int nwg = gridDim.x;
  int hw = blockIdx.x;
  int logical = hw;
  if ((nwg & 7) == 0) {
    int cpx = nwg >> 3;
    logical = (hw & 7) * cpx + (hw >> 3);
  }
  const int bPerE = nx * ny;
  const int eIdx = logical / bPerE;
  const int rem = logical - eIdx * bPerE;
  const int bx = rem / ny;            // n-panel index (consecutive logicals share it)
  const int by = rem - bx * ny;       // m-panel index
  const int expert = eGlobal + eIdx;
  const int m0 = by * 128;
  const int n0 = bx * 128;

  const unsigned short* Bexp = B + (long)eIdx * strideB;

  __shared__ unsigned short As[2][128 * 64];
  __shared__ unsigned short Bs[2][128 * 64];

  // staging geometry: dest chunk idx = q*256+tid, dest byte = idx*16,
  // row r = idx>>3, source col-byte = ((idx&7)<<4) ^ ((r&7)<<4)  (involution)
  const unsigned short* aRow[4];
  const unsigned short* bRow[4];
  int aStep[4];
#pragma unroll
  for (int q = 0; q < 4; ++q) {
    int idx = tid + q * 256;
    int r = idx >> 3;
    int cOff = ((((idx & 7) << 4) ^ ((r & 7) << 4)) >> 1);  // element offset in row
    if (MODE == 0) {
      int tok = buf[expert * cap + m0 + r];
      bool ok = (tok < Ntok);
      aRow[q] = ok ? (A + (long)tok * Kdim + cOff) : (zp + cOff);  // sentinel -> zero page
      aStep[q] = ok ? 64 : 0;
    } else {
      aRow[q] = A + (long)eIdx * strideH + (long)(m0 + r) * Kdim + cOff;
      aStep[q] = 64;
    }
    bRow[q] = Bexp + (long)(n0 + r) * Kdim + cOff;
  }

  const int wbase = wave * 64 * 8;          // wave-uniform LDS dest base (shorts)
  auto stage = [&](int b) {
#pragma unroll
    for (int q = 0; q < 4; ++q) {
      gload16(aRow[q], &As[b][wbase + q * 2048]);
      gload16(bRow[q], &Bs[b][wbase + q * 2048]);
      aRow[q] += aStep[q];
      bRow[q] += 64;
    }
  };

  f32x4 acc[4][4];
#pragma unroll
  for (int i = 0; i < 4; ++i)
#pragma unroll
    for (int j = 0; j < 4; ++j) acc[i][j] = {0.f, 0.f, 0.f, 0.f};

  const int rA = lane & 15;
  const int kByte = (lane >> 4) * 16;       // byte offset of this lane's 8-elem k-chunk

  stage(0);
  __syncthreads();                          // buf0 staged & visible

  const int nk = Kdim >> 6;
  for (int kt = 0; kt < nk; ++kt) {
    const int cur = kt & 1;
    if (kt + 1 < nk) stage(cur ^ 1);        // prefetch next tile; latency hidden under MFMA
    const char* aBase = (const char*)As[cur];
    const char* bBase = (const char*)Bs[cur];
#pragma unroll
    for (int ks = 0; ks < 2; ++ks) {
      short8 af[4], bg[4];
#pragma unroll
      for (int mi = 0; mi < 4; ++mi) {
        int row = wr * 64 + mi * 16 + rA;
        int o = (row * 128 + ks * 64 + kByte) ^ ((row & 7) << 4);
        af[mi] = *(const short8*)(aBase + o);
      }
#pragma unroll
      for (int ni = 0; ni < 4; ++ni) {
        int row = wc * 64 + ni * 16 + rA;
        int o = (row * 128 + ks * 64 + kByte) ^ ((row & 7) << 4);
        bg[ni] = *(const short8*)(bBase + o);
      }
#pragma unroll
      for (int mi = 0; mi < 4; ++mi)
#pragma unroll
        for (int ni = 0; ni < 4; ++ni)
          acc[mi][ni] = __builtin_amdgcn_mfma_f32_16x16x32_bf16(af[mi], bg[ni], acc[mi][ni], 0, 0, 0);
    }
    __syncthreads();   // drains prefetch vmcnt + protects cur buffer until all waves done
  }

  if (MODE == 0) {
    const float* b1 = bias + (long)expert * Nn;
    unsigned short* hExp = Hout + (long)eIdx * strideH;
#pragma unroll
    for (int ni = 0; ni < 4; ++ni) {
      int col = n0 + wc * 64 + ni * 16 + (lane & 15);
      float bv = b1[col];
#pragma unroll
      for (int mi = 0; mi < 4; ++mi) {
        int row0 = m0 + wr * 64 + mi * 16 + (lane >> 4) * 4;
#pragma unroll
        for (int r = 0; r < 4; ++r) {
          float v = acc[mi][ni][r] + bv;
          // tanh-approx GeLU in sigmoid form: 0.5v(1+tanh(u)) = v*sigmoid(2u)
          float gl = v / (1.f + __expf(-1.595769122f * (v + 0.044715f * v * v * v)));
          hExp[(long)(row0 + r) * Nn + col] = f2bf(gl);
        }
      }
    }
  } else {
    const float* b2 = bias + (long)expert * Nn;
#pragma unroll
    for (int mi = 0; mi < 4; ++mi) {
      int row0 = m0 + wr * 64 + mi * 16 + (lane >> 4) * 4;
#pragma unroll
      for (int r = 0; r < 4; ++r) {
        int slot = row0 + r;
        int tok = buf[expert * cap + slot];
        if (tok >= Ntok) continue;     // dropped/sentinel slot contributes nothing
        float w = wgt[expert * cap + slot];
#pragma unroll
        for (int ni = 0; ni < 4; ++ni) {
          int col = n0 + wc * 64 + ni * 16 + (lane & 15);
          float v = (acc[mi][ni][r] + b2[col]) * w;
          unsafeAtomicAdd(Fout + (long)tok * Nn + col, v);
        }
      }
    }
  }
}

// ---------------- host launcher ----------------
extern "C" void kernel_launch(void* const* d_in, const int* in_sizes, int n_in,
                              void* d_out, int out_size, void* d_ws, size_t ws_size,
                              hipStream_t stream) {
  const float* x  = (const float*)d_in[0];
  const float* Wr = (const float*)d_in[1];
  const float* br = (const float*)d_in[2];
  const float* W1 = (const float*)d_in[3];
  const float* b1 = (const float*)d_in[4];
  const float* W2 = (const float*)d_in[5];
  const float* b2 = (const float*)d_in[6];
  float* out = (float*)d_out;

  const int C = in_sizes[1] / E_NUM;            // Wr is (C,E)
  const long NC = in_sizes[0];
  const int N = (int)(NC / C);
  const int H = in_sizes[4] / E_NUM;            // b1 is (E,H)
  const int cap = N * KSEL / E_NUM;             // int(N*K/E * 1.0)

  char* p = (char*)d_ws;
  auto alloc = [&](size_t bytes) { char* r = p; p += (bytes + 255) & ~255ULL; return r; };

  unsigned short* xb = (unsigned short*)alloc((size_t)N * C * 2);
  int*   top1 = (int*)alloc((size_t)N * 4);
  int*   top2 = (int*)alloc((size_t)N * 4);
  float* g1   = (float*)alloc((size_t)N * 4);
  float* g2   = (float*)alloc((size_t)N * 4);
  int*   buf  = (int*)alloc((size_t)E_NUM * cap * 4);
  float* wgt  = (float*)alloc((size_t)E_NUM * cap * 4);
  unsigned short* zp = (unsigned short*)alloc(256);   // zero page for sentinel rows
  size_t commonBytes = (size_t)(p - (char*)d_ws);

  const size_t w1tFull = (size_t)E_NUM * C * H * 2;
  const size_t w2tFull = (size_t)E_NUM * H * C * 2;
  const size_t hFull   = (size_t)E_NUM * cap * H * 2;
  const bool full = ws_size >= commonBytes + w1tFull + w2tFull + hFull + 4096;

  hipMemsetAsync(d_out, 0, (size_t)out_size * sizeof(float), stream);
  hipMemsetAsync(zp, 0, 256, stream);
  cvt_bf16_kernel<<<(int)(((long)N * C) / (256 * 8)), 256, 0, stream>>>(x, xb, (long)N * C);
  router_kernel<<<(N + 3) / 4, 256, 0, stream>>>(x, Wr, br, N, C, top1, top2, g1, g2);
  scan_kernel<<<E_NUM, 1024, 0, stream>>>(top1, top2, g1, g2, N, cap, buf, wgt);

  if (full) {
    unsigned short* W1T = (unsigned short*)alloc(w1tFull);
    unsigned short* W2T = (unsigned short*)alloc(w2tFull);
    unsigned short* hb  = (unsigned short*)alloc(hFull);
    transpose_kernel<<<dim3(H / 64, C / 64, E_NUM), 256, 0, stream>>>(
        W1, W1T, C, H, (long)C * H, (long)C * H, 0);
    {
      int nx = H / 128, ny = cap / 128;
      moe_gemm<0><<<nx * ny * E_NUM, 256, 0, stream>>>(
          xb, W1T, buf, wgt, b1, zp, hb, nullptr, C, H, cap, N, 0,
          (long)C * H, (long)cap * H, nx, ny);
    }
    transpose_kernel<<<dim3(C / 64, H / 64, E_NUM), 256, 0, stream>>>(
        W2, W2T, H, C, (long)H * C, (long)H * C, 0);
    {
      int nx = C / 128, ny = cap / 128;
      moe_gemm<1><<<nx * ny * E_NUM, 256, 0, stream>>>(
          hb, W2T, buf, wgt, b2, zp, nullptr, out, H, C, cap, N, 0,
          (long)H * C, (long)cap * H, nx, ny);
    }
  } else {
    unsigned short* w1t = (unsigned short*)alloc((size_t)C * H * 2);
    unsigned short* w2t = (unsigned short*)alloc((size_t)H * C * 2);
    unsigned short* hb  = (unsigned short*)alloc((size_t)cap * H * 2);
    for (int e = 0; e < E_NUM; ++e) {
      transpose_kernel<<<dim3(H / 64, C / 64, 1), 256, 0, stream>>>(
          W1, w1t, C, H, (long)C * H, 0, e);
      {
        int nx = H / 128, ny = cap / 128;
        moe_gemm<0><<<nx * ny, 256, 0, stream>>>(
            xb, w1t, buf, wgt, b1, zp, hb, nullptr, C, H, cap, N, e, 0, 0, nx, ny);
      }
      transpose_kernel<<<dim3(C / 64, H / 64, 1), 256, 0, stream>>>(
          W2, w2t, H, C, (long)H * C, 0, e);
      {
        int nx = C / 128, ny = cap / 128;
        moe_gemm<1><<<nx * ny, 256, 0, stream>>>(
            hb, w2t, buf, wgt, b2, zp, nullptr, out, H, C, cap, N, e, 0, 0, nx, ny);
      }
    }
  }
}